// Round 1
// baseline (13866.621 us; speedup 1.0000x reference)
//
#include <hip/hip_runtime.h>

#define N_NODES 100000
#define N_EDGES 1600000

// ---------------- degree / edge-weight kernels ----------------

__global__ void k_deg(const int* __restrict__ src, const int* __restrict__ dst,
                      float* __restrict__ deg) {
    int e = blockIdx.x * blockDim.x + threadIdx.x;
    if (e < N_EDGES) {
        int s = src[e], d = dst[e];
        if (s != d) atomicAdd(&deg[s], 1.0f);
    }
}

__global__ void k_dinv(float* __restrict__ deg) {
    int n = blockIdx.x * blockDim.x + threadIdx.x;
    if (n < N_NODES) {
        float dg = deg[n];
        deg[n] = dg > 0.f ? rsqrtf(dg) : 0.f;
    }
}

__global__ void k_w(const int* __restrict__ src, const int* __restrict__ dst,
                    const float* __restrict__ dinv, float* __restrict__ w) {
    int e = blockIdx.x * blockDim.x + threadIdx.x;
    if (e < N_EDGES) {
        int s = src[e], d = dst[e];
        w[e] = (s != d) ? (-dinv[s] * dinv[d]) : 0.f;
    }
}

// out[i] = -a[i]
__global__ void k_negcopy(const float* __restrict__ a, float* __restrict__ o, int n) {
    int i = blockIdx.x * blockDim.x + threadIdx.x;
    if (i < n) o[i] = -a[i];
}

// ---------------- sparse propagation: out[dst] += scale*w[e]*h[src] ----------------
// one thread per (edge, 4 features); atomicAdd scatter (baseline; CSR planned next)

template <int C>
__global__ void k_prop(const float* __restrict__ h, const int* __restrict__ src,
                       const int* __restrict__ dst, const float* __restrict__ w,
                       float scale, float* __restrict__ out) {
    constexpr int F4 = C / 4;
    int tid = blockIdx.x * blockDim.x + threadIdx.x;   // max 51.2M, fits int
    if (tid >= N_EDGES * F4) return;
    int e = tid / F4;
    int f = (tid % F4) * 4;
    float we = w[e] * scale;
    int s = src[e], d = dst[e];
    const float4 v = *(const float4*)(h + (size_t)s * C + f);
    float* o = out + (size_t)d * C + f;
    atomicAdd(o + 0, we * v.x);
    atomicAdd(o + 1, we * v.y);
    atomicAdd(o + 2, we * v.z);
    atomicAdd(o + 3, we * v.w);
}

// ---------------- fused Cheb GEMM: out = [t0|t1|t2] @ W(3*CIN,COUT) + b ----------------
// 64x64 output tile, BK=32, 256 threads, 4x4 accumulators per thread, fp32.

template <int CIN, int COUT, bool RELU>
__global__ __launch_bounds__(256) void k_gemm(const float* __restrict__ t0,
                                              const float* __restrict__ t1,
                                              const float* __restrict__ t2,
                                              const float* __restrict__ W,
                                              const float* __restrict__ bias,
                                              float* __restrict__ out) {
    constexpr int BM = 64, BN = 64, BK = 32;
    constexpr int KT = 3 * CIN;
    __shared__ float sa[BK][BM + 4];   // A^T tile; stride 68 floats: 16B-aligned rows
    __shared__ float sb[BK][BN];       // B tile
    const int m0 = blockIdx.x * BM;
    const int n0 = blockIdx.y * BN;
    const int tid = threadIdx.x;
    const int trow = tid / 16, tcol = tid % 16;

    float acc[4][4] = {};
    const float* tbuf[3] = {t0, t1, t2};

    for (int kb = 0; kb < KT; kb += BK) {
        const float* tb = tbuf[kb / CIN];
        const int cib = kb % CIN;
        // A tile: rows m0..m0+63, k-cols kb..kb+31  (scalar coalesced loads)
        #pragma unroll
        for (int i = 0; i < 8; i++) {
            int flat = tid + i * 256;      // [64][32]
            int m = flat >> 5, kk = flat & 31;
            int node = m0 + m;
            float v = 0.f;
            if (node < N_NODES) v = tb[(size_t)node * CIN + cib + kk];
            sa[kk][m] = v;
        }
        // B tile: W rows kb..kb+31, cols n0..n0+63 (float4 loads)
        #pragma unroll
        for (int i = 0; i < 2; i++) {
            int f4 = tid + i * 256;        // [32][16] float4s
            int r = f4 >> 4, c4 = f4 & 15;
            float4 v = *(const float4*)&W[(size_t)(kb + r) * COUT + n0 + c4 * 4];
            *(float4*)&sb[r][c4 * 4] = v;
        }
        __syncthreads();
        #pragma unroll
        for (int kk = 0; kk < BK; kk++) {
            const float4 av = *(const float4*)&sa[kk][trow * 4];
            const float4 bv = *(const float4*)&sb[kk][tcol * 4];
            const float a[4] = {av.x, av.y, av.z, av.w};
            const float b[4] = {bv.x, bv.y, bv.z, bv.w};
            #pragma unroll
            for (int i = 0; i < 4; i++)
                #pragma unroll
                for (int j = 0; j < 4; j++) acc[i][j] += a[i] * b[j];
        }
        __syncthreads();
    }

    #pragma unroll
    for (int i = 0; i < 4; i++) {
        int node = m0 + trow * 4 + i;
        if (node < N_NODES) {
            #pragma unroll
            for (int j = 0; j < 4; j++) {
                int co = n0 + tcol * 4 + j;
                float v = acc[i][j] + bias[co];
                if (RELU) v = fmaxf(v, 0.f);
                out[(size_t)node * COUT + co] = v;
            }
        }
    }
}

// ---------------- launch ----------------

static inline int ceil_div(int a, int b) { return (a + b - 1) / b; }

extern "C" void kernel_launch(void* const* d_in, const int* in_sizes, int n_in,
                              void* d_out, int out_size, void* d_ws, size_t ws_size,
                              hipStream_t stream) {
    const float* x   = (const float*)d_in[0];
    const int*   ei  = (const int*)d_in[1];      // int64 inputs delivered as int32
    const int*   src = ei;
    const int*   dst = ei + N_EDGES;
    const float* W1 = (const float*)d_in[3];
    const float* b1 = (const float*)d_in[4];
    const float* W2 = (const float*)d_in[5];
    const float* b2 = (const float*)d_in[6];
    const float* W3 = (const float*)d_in[7];
    const float* b3 = (const float*)d_in[8];
    float* out = (float*)d_out;

    // workspace layout (floats): dinv | w | tx1(128) | tx2(128) | h1(64) | h2(128)
    float* p    = (float*)d_ws;
    float* dinv = p;  p += N_NODES;
    float* w    = p;  p += N_EDGES;
    float* tx1  = p;  p += (size_t)N_NODES * 128;
    float* tx2  = p;  p += (size_t)N_NODES * 128;
    float* h1   = p;  p += (size_t)N_NODES * 64;
    float* h2   = p;  p += (size_t)N_NODES * 128;

    const int TB = 256;
    const int gE = ceil_div(N_EDGES, TB);
    const int gN = ceil_div(N_NODES, TB);

    // edge weights
    hipMemsetAsync(dinv, 0, N_NODES * sizeof(float), stream);
    k_deg<<<gE, TB, 0, stream>>>(src, dst, dinv);
    k_dinv<<<gN, TB, 0, stream>>>(dinv);
    k_w<<<gE, TB, 0, stream>>>(src, dst, dinv, w);

    // ---- layer 1: 128 -> 64, relu ----
    {
        const int C = 128, F4 = C / 4;
        const int gP = ceil_div(N_EDGES * F4, TB);
        const int nEl = N_NODES * C;
        hipMemsetAsync(tx1, 0, (size_t)nEl * sizeof(float), stream);
        k_prop<128><<<gP, TB, 0, stream>>>(x, src, dst, w, 1.f, tx1);
        k_negcopy<<<ceil_div(nEl, TB), TB, 0, stream>>>(x, tx2, nEl);
        k_prop<128><<<gP, TB, 0, stream>>>(tx1, src, dst, w, 2.f, tx2);
        dim3 g(ceil_div(N_NODES, 64), 64 / 64);
        k_gemm<128, 64, true><<<g, TB, 0, stream>>>(x, tx1, tx2, W1, b1, h1);
    }
    // ---- layer 2: 64 -> 128, relu ----
    {
        const int C = 64, F4 = C / 4;
        const int gP = ceil_div(N_EDGES * F4, TB);
        const int nEl = N_NODES * C;
        hipMemsetAsync(tx1, 0, (size_t)nEl * sizeof(float), stream);
        k_prop<64><<<gP, TB, 0, stream>>>(h1, src, dst, w, 1.f, tx1);
        k_negcopy<<<ceil_div(nEl, TB), TB, 0, stream>>>(h1, tx2, nEl);
        k_prop<64><<<gP, TB, 0, stream>>>(tx1, src, dst, w, 2.f, tx2);
        dim3 g(ceil_div(N_NODES, 64), 128 / 64);
        k_gemm<64, 128, true><<<g, TB, 0, stream>>>(h1, tx1, tx2, W2, b2, h2);
    }
    // ---- layer 3: 128 -> 256, no relu ----
    {
        const int C = 128, F4 = C / 4;
        const int gP = ceil_div(N_EDGES * F4, TB);
        const int nEl = N_NODES * C;
        hipMemsetAsync(tx1, 0, (size_t)nEl * sizeof(float), stream);
        k_prop<128><<<gP, TB, 0, stream>>>(h2, src, dst, w, 1.f, tx1);
        k_negcopy<<<ceil_div(nEl, TB), TB, 0, stream>>>(h2, tx2, nEl);
        k_prop<128><<<gP, TB, 0, stream>>>(tx1, src, dst, w, 2.f, tx2);
        dim3 g(ceil_div(N_NODES, 64), 256 / 64);
        k_gemm<128, 256, false><<<g, TB, 0, stream>>>(h2, tx1, tx2, W3, b3, out);
    }
}

// Round 2
// 1691.252 us; speedup vs baseline: 8.1990x; 8.1990x over previous
//
#include <hip/hip_runtime.h>

#define N_NODES 100000
#define N_EDGES 1600000

// ---------------- degree kernels ----------------

// out-degree (float, for dinv) by src; in-degree (int, for CSR) by dst; both exclude self-loops
__global__ void k_degboth(const int* __restrict__ src, const int* __restrict__ dst,
                          float* __restrict__ degout, int* __restrict__ degin) {
    int e = blockIdx.x * blockDim.x + threadIdx.x;
    if (e < N_EDGES) {
        int s = src[e], d = dst[e];
        if (s != d) {
            atomicAdd(&degout[s], 1.0f);
            atomicAdd(&degin[d], 1);
        }
    }
}

__global__ void k_dinv(float* __restrict__ deg) {
    int n = blockIdx.x * blockDim.x + threadIdx.x;
    if (n < N_NODES) {
        float dg = deg[n];
        deg[n] = dg > 0.f ? rsqrtf(dg) : 0.f;
    }
}

// ---------------- single-block exclusive scan (shfl + LDS), writes rp and cursor ----------------

__global__ __launch_bounds__(1024) void k_scan(const int* __restrict__ degin,
                                               int* __restrict__ rp, int* __restrict__ cursor) {
    __shared__ int ws[16];
    __shared__ int carry;
    const int tid = threadIdx.x;
    const int lane = tid & 63, wid = tid >> 6;
    if (tid == 0) carry = 0;
    __syncthreads();
    for (int base = 0; base < N_NODES; base += 1024) {
        int i = base + tid;
        int v = (i < N_NODES) ? degin[i] : 0;
        // wave inclusive scan
        int incl = v;
        #pragma unroll
        for (int off = 1; off < 64; off <<= 1) {
            int t = __shfl_up(incl, off, 64);
            if (lane >= off) incl += t;
        }
        if (lane == 63) ws[wid] = incl;
        __syncthreads();
        int offset = 0;
        for (int j = 0; j < wid; j++) offset += ws[j];
        int total = 0;
        #pragma unroll
        for (int j = 0; j < 16; j++) total += ws[j];
        int excl = carry + offset + incl - v;
        if (i < N_NODES) { rp[i] = excl; cursor[i] = excl; }
        __syncthreads();            // everyone done reading ws/carry
        if (tid == 0) carry += total;
        __syncthreads();
    }
    if (tid == 0) rp[N_NODES] = carry;
}

// ---------------- scatter edges into CSR slots, computing weights ----------------

__global__ void k_scatter(const int* __restrict__ src, const int* __restrict__ dst,
                          const float* __restrict__ dinv, int* __restrict__ cursor,
                          int* __restrict__ col, float* __restrict__ val) {
    int e = blockIdx.x * blockDim.x + threadIdx.x;
    if (e < N_EDGES) {
        int s = src[e], d = dst[e];
        if (s != d) {
            int pos = atomicAdd(&cursor[d], 1);
            col[pos] = s;
            val[pos] = -dinv[s] * dinv[d];
        }
    }
}

// ---------------- gather propagation: out[n] = alpha*sum_e val*h[col] (+ beta*init[n]) ----------------
// one block of C threads per dst node; edge list staged through LDS in chunks

template <int C>
__global__ __launch_bounds__(C) void k_gather(const float* __restrict__ h,
                                              const int* __restrict__ rp,
                                              const int* __restrict__ col,
                                              const float* __restrict__ val,
                                              float alpha, const float* __restrict__ init,
                                              float beta, float* __restrict__ out) {
    constexpr int CH = 64;
    __shared__ int scol[CH];
    __shared__ float sval[CH];
    const int n = blockIdx.x;
    const int f = threadIdx.x;
    const int beg = rp[n], end = rp[n + 1];
    float acc = 0.f;
    for (int cs = beg; cs < end; cs += CH) {
        const int m = min(CH, end - cs);
        if (f < CH && f < m) { scol[f] = col[cs + f]; sval[f] = val[cs + f]; }
        __syncthreads();
        for (int j = 0; j < m; j++)
            acc += sval[j] * h[(size_t)scol[j] * C + f];
        __syncthreads();
    }
    float v = alpha * acc;
    if (init) v += beta * init[(size_t)n * C + f];
    out[(size_t)n * C + f] = v;
}

// ---------------- fused Cheb GEMM: out = [t0|t1|t2] @ W(3*CIN,COUT) + b ----------------

template <int CIN, int COUT, bool RELU>
__global__ __launch_bounds__(256) void k_gemm(const float* __restrict__ t0,
                                              const float* __restrict__ t1,
                                              const float* __restrict__ t2,
                                              const float* __restrict__ W,
                                              const float* __restrict__ bias,
                                              float* __restrict__ out) {
    constexpr int BM = 64, BN = 64, BK = 32;
    constexpr int KT = 3 * CIN;
    __shared__ float sa[BK][BM + 4];
    __shared__ float sb[BK][BN];
    const int m0 = blockIdx.x * BM;
    const int n0 = blockIdx.y * BN;
    const int tid = threadIdx.x;
    const int trow = tid / 16, tcol = tid % 16;

    float acc[4][4] = {};
    const float* tbuf[3] = {t0, t1, t2};

    for (int kb = 0; kb < KT; kb += BK) {
        const float* tb = tbuf[kb / CIN];
        const int cib = kb % CIN;
        #pragma unroll
        for (int i = 0; i < 8; i++) {
            int flat = tid + i * 256;      // [64][32]
            int m = flat >> 5, kk = flat & 31;
            int node = m0 + m;
            float v = 0.f;
            if (node < N_NODES) v = tb[(size_t)node * CIN + cib + kk];
            sa[kk][m] = v;
        }
        #pragma unroll
        for (int i = 0; i < 2; i++) {
            int f4 = tid + i * 256;        // [32][16] float4s
            int r = f4 >> 4, c4 = f4 & 15;
            float4 v = *(const float4*)&W[(size_t)(kb + r) * COUT + n0 + c4 * 4];
            *(float4*)&sb[r][c4 * 4] = v;
        }
        __syncthreads();
        #pragma unroll
        for (int kk = 0; kk < BK; kk++) {
            const float4 av = *(const float4*)&sa[kk][trow * 4];
            const float4 bv = *(const float4*)&sb[kk][tcol * 4];
            const float a[4] = {av.x, av.y, av.z, av.w};
            const float b[4] = {bv.x, bv.y, bv.z, bv.w};
            #pragma unroll
            for (int i = 0; i < 4; i++)
                #pragma unroll
                for (int j = 0; j < 4; j++) acc[i][j] += a[i] * b[j];
        }
        __syncthreads();
    }

    #pragma unroll
    for (int i = 0; i < 4; i++) {
        int node = m0 + trow * 4 + i;
        if (node < N_NODES) {
            #pragma unroll
            for (int j = 0; j < 4; j++) {
                int co = n0 + tcol * 4 + j;
                float v = acc[i][j] + bias[co];
                if (RELU) v = fmaxf(v, 0.f);
                out[(size_t)node * COUT + co] = v;
            }
        }
    }
}

// ---------------- launch ----------------

static inline int ceil_div(int a, int b) { return (a + b - 1) / b; }

extern "C" void kernel_launch(void* const* d_in, const int* in_sizes, int n_in,
                              void* d_out, int out_size, void* d_ws, size_t ws_size,
                              hipStream_t stream) {
    const float* x   = (const float*)d_in[0];
    const int*   ei  = (const int*)d_in[1];
    const int*   src = ei;
    const int*   dst = ei + N_EDGES;
    const float* W1 = (const float*)d_in[3];
    const float* b1 = (const float*)d_in[4];
    const float* W2 = (const float*)d_in[5];
    const float* b2 = (const float*)d_in[6];
    const float* W3 = (const float*)d_in[7];
    const float* b3 = (const float*)d_in[8];
    float* out = (float*)d_out;

    // workspace layout
    float* p     = (float*)d_ws;
    float* dinv  = p;              p += N_NODES;
    int*   degin = (int*)p;        p += N_NODES;
    int*   rp    = (int*)p;        p += N_NODES + 1;
    int*   cursor= (int*)p;        p += N_NODES;
    int*   col   = (int*)p;        p += N_EDGES;
    float* val   = p;              p += N_EDGES;
    float* tx1   = p;              p += (size_t)N_NODES * 128;
    float* tx2   = p;              p += (size_t)N_NODES * 128;
    float* h1    = p;              p += (size_t)N_NODES * 64;
    float* h2    = p;              p += (size_t)N_NODES * 128;

    const int TB = 256;
    const int gE = ceil_div(N_EDGES, TB);
    const int gN = ceil_div(N_NODES, TB);

    // ---- build edge weights + dst-CSR ----
    hipMemsetAsync(dinv, 0, N_NODES * sizeof(float), stream);
    hipMemsetAsync(degin, 0, N_NODES * sizeof(int), stream);
    k_degboth<<<gE, TB, 0, stream>>>(src, dst, dinv, degin);
    k_dinv<<<gN, TB, 0, stream>>>(dinv);
    k_scan<<<1, 1024, 0, stream>>>(degin, rp, cursor);
    k_scatter<<<gE, TB, 0, stream>>>(src, dst, dinv, cursor, col, val);

    // ---- layer 1: 128 -> 64, relu ----
    k_gather<128><<<N_NODES, 128, 0, stream>>>(x, rp, col, val, 1.f, nullptr, 0.f, tx1);
    k_gather<128><<<N_NODES, 128, 0, stream>>>(tx1, rp, col, val, 2.f, x, -1.f, tx2);
    {
        dim3 g(ceil_div(N_NODES, 64), 1);
        k_gemm<128, 64, true><<<g, TB, 0, stream>>>(x, tx1, tx2, W1, b1, h1);
    }
    // ---- layer 2: 64 -> 128, relu ----
    k_gather<64><<<N_NODES, 64, 0, stream>>>(h1, rp, col, val, 1.f, nullptr, 0.f, tx1);
    k_gather<64><<<N_NODES, 64, 0, stream>>>(tx1, rp, col, val, 2.f, h1, -1.f, tx2);
    {
        dim3 g(ceil_div(N_NODES, 64), 2);
        k_gemm<64, 128, true><<<g, TB, 0, stream>>>(h1, tx1, tx2, W2, b2, h2);
    }
    // ---- layer 3: 128 -> 256, no relu ----
    k_gather<128><<<N_NODES, 128, 0, stream>>>(h2, rp, col, val, 1.f, nullptr, 0.f, tx1);
    k_gather<128><<<N_NODES, 128, 0, stream>>>(tx1, rp, col, val, 2.f, h2, -1.f, tx2);
    {
        dim3 g(ceil_div(N_NODES, 64), 4);
        k_gemm<128, 256, false><<<g, TB, 0, stream>>>(h2, tx1, tx2, W3, b3, out);
    }
}

// Round 3
// 1274.037 us; speedup vs baseline: 10.8840x; 1.3275x over previous
//
#include <hip/hip_runtime.h>

#define N_NODES 100000
#define N_EDGES 1600000

typedef short short8 __attribute__((ext_vector_type(8)));
typedef float f32x4 __attribute__((ext_vector_type(4)));

__device__ __forceinline__ unsigned short f2b(float f) {
    unsigned u = __builtin_bit_cast(unsigned, f);
    u += 0x7fffu + ((u >> 16) & 1u);          // RNE
    return (unsigned short)(u >> 16);
}
__device__ __forceinline__ float b2f_lo(unsigned p) {   // low bf16 of a pair
    return __builtin_bit_cast(float, p << 16);
}
__device__ __forceinline__ float b2f_hi(unsigned p) {   // high bf16 of a pair
    return __builtin_bit_cast(float, p & 0xffff0000u);
}
__device__ __forceinline__ float b2f(unsigned short s) {
    return __builtin_bit_cast(float, ((unsigned)s) << 16);
}

// ---------------- fp32 -> bf16 bulk convert (n multiple of 4) ----------------
__global__ void k_f2b(const float* __restrict__ in, unsigned short* __restrict__ out, int n4) {
    int i = blockIdx.x * blockDim.x + threadIdx.x;
    if (i < n4) {
        float4 v = ((const float4*)in)[i];
        uint2 o;
        o.x = (unsigned)f2b(v.x) | ((unsigned)f2b(v.y) << 16);
        o.y = (unsigned)f2b(v.z) | ((unsigned)f2b(v.w) << 16);
        ((uint2*)out)[i] = o;
    }
}

// ---------------- W[3*CIN][COUT] fp32 -> Wt[COUT][3*CIN] bf16 ----------------
__global__ void k_wt(const float* __restrict__ W, unsigned short* __restrict__ Wt,
                     int KT, int COUT) {
    int i = blockIdx.x * blockDim.x + threadIdx.x;
    if (i < KT * COUT) {
        int k = i % KT, n = i / KT;
        Wt[(size_t)n * KT + k] = f2b(W[(size_t)k * COUT + n]);
    }
}

// ---------------- degree kernels ----------------
__global__ void k_degboth(const int* __restrict__ src, const int* __restrict__ dst,
                          float* __restrict__ degout, int* __restrict__ degin) {
    int e = blockIdx.x * blockDim.x + threadIdx.x;
    if (e < N_EDGES) {
        int s = src[e], d = dst[e];
        if (s != d) {
            atomicAdd(&degout[s], 1.0f);
            atomicAdd(&degin[d], 1);
        }
    }
}

__global__ void k_dinv(float* __restrict__ deg) {
    int n = blockIdx.x * blockDim.x + threadIdx.x;
    if (n < N_NODES) {
        float dg = deg[n];
        deg[n] = dg > 0.f ? rsqrtf(dg) : 0.f;
    }
}

// ---------------- single-block exclusive scan ----------------
__global__ __launch_bounds__(1024) void k_scan(const int* __restrict__ degin,
                                               int* __restrict__ rp, int* __restrict__ cursor) {
    __shared__ int ws[16];
    __shared__ int carry;
    const int tid = threadIdx.x;
    const int lane = tid & 63, wid = tid >> 6;
    if (tid == 0) carry = 0;
    __syncthreads();
    for (int base = 0; base < N_NODES; base += 1024) {
        int i = base + tid;
        int v = (i < N_NODES) ? degin[i] : 0;
        int incl = v;
        #pragma unroll
        for (int off = 1; off < 64; off <<= 1) {
            int t = __shfl_up(incl, off, 64);
            if (lane >= off) incl += t;
        }
        if (lane == 63) ws[wid] = incl;
        __syncthreads();
        int offset = 0;
        for (int j = 0; j < wid; j++) offset += ws[j];
        int total = 0;
        #pragma unroll
        for (int j = 0; j < 16; j++) total += ws[j];
        int excl = carry + offset + incl - v;
        if (i < N_NODES) { rp[i] = excl; cursor[i] = excl; }
        __syncthreads();
        if (tid == 0) carry += total;
        __syncthreads();
    }
    if (tid == 0) rp[N_NODES] = carry;
}

// ---------------- scatter edges into CSR slots ----------------
__global__ void k_scatter(const int* __restrict__ src, const int* __restrict__ dst,
                          const float* __restrict__ dinv, int* __restrict__ cursor,
                          int* __restrict__ col, float* __restrict__ val) {
    int e = blockIdx.x * blockDim.x + threadIdx.x;
    if (e < N_EDGES) {
        int s = src[e], d = dst[e];
        if (s != d) {
            int pos = atomicAdd(&cursor[d], 1);
            col[pos] = s;
            val[pos] = -dinv[s] * dinv[d];
        }
    }
}

// ---------------- bf16 gather: out[n] = alpha*sum val*h[col] (+ beta*init[n]) ----------------
// one 64-thread block per dst node; h/init/out bf16, accumulate fp32
template <int C>
__global__ __launch_bounds__(64) void k_gatherb(const unsigned short* __restrict__ h,
                                                const int* __restrict__ rp,
                                                const int* __restrict__ col,
                                                const float* __restrict__ val,
                                                float alpha, const unsigned short* __restrict__ init,
                                                float beta, unsigned short* __restrict__ out) {
    __shared__ int scol[64];
    __shared__ float sval[64];
    const int n = blockIdx.x;
    const int lane = threadIdx.x;
    const int beg = rp[n], end = rp[n + 1];

    if (C == 128) {
        const unsigned* h2 = (const unsigned*)h;
        float ax = 0.f, ay = 0.f;
        for (int cs = beg; cs < end; cs += 64) {
            const int m = min(64, end - cs);
            if (lane < m) { scol[lane] = col[cs + lane]; sval[lane] = val[cs + lane]; }
            __syncthreads();
            int j = 0;
            for (; j + 2 <= m; j += 2) {
                unsigned p0 = h2[(size_t)scol[j] * 64 + lane];     float w0 = sval[j];
                unsigned p1 = h2[(size_t)scol[j + 1] * 64 + lane]; float w1 = sval[j + 1];
                ax = fmaf(w0, b2f_lo(p0), ax); ay = fmaf(w0, b2f_hi(p0), ay);
                ax = fmaf(w1, b2f_lo(p1), ax); ay = fmaf(w1, b2f_hi(p1), ay);
            }
            if (j < m) {
                unsigned p0 = h2[(size_t)scol[j] * 64 + lane]; float w0 = sval[j];
                ax = fmaf(w0, b2f_lo(p0), ax); ay = fmaf(w0, b2f_hi(p0), ay);
            }
            __syncthreads();
        }
        float vx = alpha * ax, vy = alpha * ay;
        if (init) {
            unsigned ip = ((const unsigned*)init)[(size_t)n * 64 + lane];
            vx = fmaf(beta, b2f_lo(ip), vx);
            vy = fmaf(beta, b2f_hi(ip), vy);
        }
        ((unsigned*)out)[(size_t)n * 64 + lane] =
            (unsigned)f2b(vx) | ((unsigned)f2b(vy) << 16);
    } else {   // C == 64: one feature per lane
        float a = 0.f;
        for (int cs = beg; cs < end; cs += 64) {
            const int m = min(64, end - cs);
            if (lane < m) { scol[lane] = col[cs + lane]; sval[lane] = val[cs + lane]; }
            __syncthreads();
            int j = 0;
            for (; j + 2 <= m; j += 2) {
                float v0 = b2f(h[(size_t)scol[j] * 64 + lane]);
                float v1 = b2f(h[(size_t)scol[j + 1] * 64 + lane]);
                a = fmaf(sval[j], v0, a);
                a = fmaf(sval[j + 1], v1, a);
            }
            if (j < m) a = fmaf(sval[j], b2f(h[(size_t)scol[j] * 64 + lane]), a);
            __syncthreads();
        }
        float v = alpha * a;
        if (init) v = fmaf(beta, b2f(init[(size_t)n * 64 + lane]), v);
        out[(size_t)n * 64 + lane] = f2b(v);
    }
}

// ---------------- MFMA bf16 GEMM: out = [t0|t1|t2] @ Wt^T + b ----------------
// block = 256 thr (4 waves); each wave: 16-row strip x full COUT.
// A frag: 8 contiguous k per lane from row-major t-buffers.
// B frag: 8 contiguous k per lane from Wt[n][k] (pre-transposed bf16).
template <int CIN, int COUT, bool RELU, bool BF16OUT>
__global__ __launch_bounds__(256) void k_mm(const unsigned short* __restrict__ t0,
                                            const unsigned short* __restrict__ t1,
                                            const unsigned short* __restrict__ t2,
                                            const unsigned short* __restrict__ Wt,
                                            const float* __restrict__ bias,
                                            void* __restrict__ outv) {
    constexpr int KT = 3 * CIN;
    constexpr int NT = COUT / 16;
    const int wave = threadIdx.x >> 6;
    const int lane = threadIdx.x & 63;
    const int l16 = lane & 15;
    const int quad = lane >> 4;
    const int mBase = blockIdx.x * 64 + wave * 16;
    const int arow = mBase + l16;
    const bool inA = arow < N_NODES;

    f32x4 acc[NT];
    #pragma unroll
    for (int nt = 0; nt < NT; nt++) acc[nt] = (f32x4){0.f, 0.f, 0.f, 0.f};

    const unsigned short* tb[3] = {t0, t1, t2};

    #pragma unroll
    for (int kt = 0; kt < KT / 32; kt++) {
        const int kb = kt * 32;
        const unsigned short* t = tb[kb / CIN];
        const int kin = kb % CIN;
        short8 afrag = {0, 0, 0, 0, 0, 0, 0, 0};
        if (inA) afrag = *(const short8*)(t + (size_t)arow * CIN + kin + quad * 8);
        #pragma unroll
        for (int nt = 0; nt < NT; nt++) {
            const short8 bfrag =
                *(const short8*)(Wt + (size_t)(nt * 16 + l16) * KT + kb + quad * 8);
            acc[nt] = __builtin_amdgcn_mfma_f32_16x16x32_bf16(afrag, bfrag, acc[nt], 0, 0, 0);
        }
    }

    // C/D layout: col = lane&15, row = quad*4 + reg
    #pragma unroll
    for (int nt = 0; nt < NT; nt++) {
        #pragma unroll
        for (int r = 0; r < 4; r++) {
            const int node = mBase + quad * 4 + r;
            if (node < N_NODES) {
                const int co = nt * 16 + l16;
                float o = acc[nt][r] + bias[co];
                if (RELU) o = fmaxf(o, 0.f);
                if (BF16OUT)
                    ((unsigned short*)outv)[(size_t)node * COUT + co] = f2b(o);
                else
                    ((float*)outv)[(size_t)node * COUT + co] = o;
            }
        }
    }
}

// ---------------- launch ----------------
static inline int ceil_div(int a, int b) { return (a + b - 1) / b; }

extern "C" void kernel_launch(void* const* d_in, const int* in_sizes, int n_in,
                              void* d_out, int out_size, void* d_ws, size_t ws_size,
                              hipStream_t stream) {
    const float* x   = (const float*)d_in[0];
    const int*   ei  = (const int*)d_in[1];
    const int*   src = ei;
    const int*   dst = ei + N_EDGES;
    const float* W1 = (const float*)d_in[3];
    const float* b1 = (const float*)d_in[4];
    const float* W2 = (const float*)d_in[5];
    const float* b2 = (const float*)d_in[6];
    const float* W3 = (const float*)d_in[7];
    const float* b3 = (const float*)d_in[8];
    float* out = (float*)d_out;

    // workspace layout
    char* p = (char*)d_ws;
    float* dinv   = (float*)p;           p += (size_t)N_NODES * 4;
    int*   degin  = (int*)p;             p += (size_t)N_NODES * 4;
    int*   rp     = (int*)p;             p += (size_t)(N_NODES + 4) * 4;   // padded for alignment
    int*   cursor = (int*)p;             p += (size_t)N_NODES * 4;
    int*   col    = (int*)p;             p += (size_t)N_EDGES * 4;
    float* val    = (float*)p;           p += (size_t)N_EDGES * 4;
    unsigned short* xb   = (unsigned short*)p; p += (size_t)N_NODES * 128 * 2;
    unsigned short* tx1b = (unsigned short*)p; p += (size_t)N_NODES * 128 * 2;
    unsigned short* tx2b = (unsigned short*)p; p += (size_t)N_NODES * 128 * 2;
    unsigned short* h1b  = (unsigned short*)p; p += (size_t)N_NODES * 64 * 2;
    unsigned short* h2b  = (unsigned short*)p; p += (size_t)N_NODES * 128 * 2;
    unsigned short* Wt1  = (unsigned short*)p; p += (size_t)64 * 384 * 2;
    unsigned short* Wt2  = (unsigned short*)p; p += (size_t)128 * 192 * 2;
    unsigned short* Wt3  = (unsigned short*)p; p += (size_t)256 * 384 * 2;

    const int TB = 256;
    const int gE = ceil_div(N_EDGES, TB);
    const int gN = ceil_div(N_NODES, TB);
    const int gMM = ceil_div(N_NODES, 64);

    // conversions
    k_f2b<<<ceil_div(N_NODES * 128 / 4, TB), TB, 0, stream>>>(x, xb, N_NODES * 128 / 4);
    k_wt<<<ceil_div(384 * 64, TB), TB, 0, stream>>>(W1, Wt1, 384, 64);
    k_wt<<<ceil_div(192 * 128, TB), TB, 0, stream>>>(W2, Wt2, 192, 128);
    k_wt<<<ceil_div(384 * 256, TB), TB, 0, stream>>>(W3, Wt3, 384, 256);

    // edge weights + dst-CSR
    hipMemsetAsync(dinv, 0, N_NODES * sizeof(float), stream);
    hipMemsetAsync(degin, 0, N_NODES * sizeof(int), stream);
    k_degboth<<<gE, TB, 0, stream>>>(src, dst, dinv, degin);
    k_dinv<<<gN, TB, 0, stream>>>(dinv);
    k_scan<<<1, 1024, 0, stream>>>(degin, rp, cursor);
    k_scatter<<<gE, TB, 0, stream>>>(src, dst, dinv, cursor, col, val);

    // ---- layer 1: 128 -> 64, relu ----
    k_gatherb<128><<<N_NODES, 64, 0, stream>>>(xb, rp, col, val, 1.f, nullptr, 0.f, tx1b);
    k_gatherb<128><<<N_NODES, 64, 0, stream>>>(tx1b, rp, col, val, 2.f, xb, -1.f, tx2b);
    k_mm<128, 64, true, true><<<gMM, TB, 0, stream>>>(xb, tx1b, tx2b, Wt1, b1, h1b);

    // ---- layer 2: 64 -> 128, relu ----
    k_gatherb<64><<<N_NODES, 64, 0, stream>>>(h1b, rp, col, val, 1.f, nullptr, 0.f, tx1b);
    k_gatherb<64><<<N_NODES, 64, 0, stream>>>(tx1b, rp, col, val, 2.f, h1b, -1.f, tx2b);
    k_mm<64, 128, true, true><<<gMM, TB, 0, stream>>>(h1b, tx1b, tx2b, Wt2, b2, h2b);

    // ---- layer 3: 128 -> 256, no relu ----
    k_gatherb<128><<<N_NODES, 64, 0, stream>>>(h2b, rp, col, val, 1.f, nullptr, 0.f, tx1b);
    k_gatherb<128><<<N_NODES, 64, 0, stream>>>(tx1b, rp, col, val, 2.f, h2b, -1.f, tx2b);
    k_mm<128, 256, false, false><<<gMM, TB, 0, stream>>>(h2b, tx1b, tx2b, Wt3, b3, out);
}

// Round 4
// 1105.425 us; speedup vs baseline: 12.5442x; 1.1525x over previous
//
#include <hip/hip_runtime.h>

#define N_NODES 100000
#define N_EDGES 1600000

typedef short short8 __attribute__((ext_vector_type(8)));
typedef float f32x4 __attribute__((ext_vector_type(4)));

__device__ __forceinline__ unsigned short f2b(float f) {
    unsigned u = __builtin_bit_cast(unsigned, f);
    u += 0x7fffu + ((u >> 16) & 1u);          // RNE
    return (unsigned short)(u >> 16);
}
__device__ __forceinline__ float b2f_lo(unsigned p) {
    return __builtin_bit_cast(float, p << 16);
}
__device__ __forceinline__ float b2f_hi(unsigned p) {
    return __builtin_bit_cast(float, p & 0xffff0000u);
}
__device__ __forceinline__ float b2f(unsigned short s) {
    return __builtin_bit_cast(float, ((unsigned)s) << 16);
}

// ---------------- fp32 -> bf16 bulk convert ----------------
__global__ void k_f2b(const float* __restrict__ in, unsigned short* __restrict__ out, int n4) {
    int i = blockIdx.x * blockDim.x + threadIdx.x;
    if (i < n4) {
        float4 v = ((const float4*)in)[i];
        uint2 o;
        o.x = (unsigned)f2b(v.x) | ((unsigned)f2b(v.y) << 16);
        o.y = (unsigned)f2b(v.z) | ((unsigned)f2b(v.w) << 16);
        ((uint2*)out)[i] = o;
    }
}

// ---------------- W[3*CIN][COUT] fp32 -> Wt[COUT][3*CIN] bf16 ----------------
__global__ void k_wt(const float* __restrict__ W, unsigned short* __restrict__ Wt,
                     int KT, int COUT) {
    int i = blockIdx.x * blockDim.x + threadIdx.x;
    if (i < KT * COUT) {
        int k = i % KT, n = i / KT;
        Wt[(size_t)n * KT + k] = f2b(W[(size_t)k * COUT + n]);
    }
}

// ---------------- degree kernels ----------------
__global__ void k_degboth(const int* __restrict__ src, const int* __restrict__ dst,
                          float* __restrict__ degout, int* __restrict__ degin) {
    int e = blockIdx.x * blockDim.x + threadIdx.x;
    if (e < N_EDGES) {
        int s = src[e], d = dst[e];
        if (s != d) {
            atomicAdd(&degout[s], 1.0f);
            atomicAdd(&degin[d], 1);
        }
    }
}

__global__ void k_dinv(float* __restrict__ deg) {
    int n = blockIdx.x * blockDim.x + threadIdx.x;
    if (n < N_NODES) {
        float dg = deg[n];
        deg[n] = dg > 0.f ? rsqrtf(dg) : 0.f;
    }
}

// ---------------- single-block exclusive scan ----------------
__global__ __launch_bounds__(1024) void k_scan(const int* __restrict__ degin,
                                               int* __restrict__ rp, int* __restrict__ cursor) {
    __shared__ int ws[16];
    __shared__ int carry;
    const int tid = threadIdx.x;
    const int lane = tid & 63, wid = tid >> 6;
    if (tid == 0) carry = 0;
    __syncthreads();
    for (int base = 0; base < N_NODES; base += 1024) {
        int i = base + tid;
        int v = (i < N_NODES) ? degin[i] : 0;
        int incl = v;
        #pragma unroll
        for (int off = 1; off < 64; off <<= 1) {
            int t = __shfl_up(incl, off, 64);
            if (lane >= off) incl += t;
        }
        if (lane == 63) ws[wid] = incl;
        __syncthreads();
        int offset = 0;
        for (int j = 0; j < wid; j++) offset += ws[j];
        int total = 0;
        #pragma unroll
        for (int j = 0; j < 16; j++) total += ws[j];
        int excl = carry + offset + incl - v;
        if (i < N_NODES) { rp[i] = excl; cursor[i] = excl; }
        __syncthreads();
        if (tid == 0) carry += total;
        __syncthreads();
    }
    if (tid == 0) rp[N_NODES] = carry;
}

// ---------------- scatter edges into CSR slots as (col,val) pairs ----------------
__global__ void k_scatter(const int* __restrict__ src, const int* __restrict__ dst,
                          const float* __restrict__ dinv, int* __restrict__ cursor,
                          uint2* __restrict__ ep) {
    int e = blockIdx.x * blockDim.x + threadIdx.x;
    if (e < N_EDGES) {
        int s = src[e], d = dst[e];
        if (s != d) {
            int pos = atomicAdd(&cursor[d], 1);
            float v = -dinv[s] * dinv[d];
            uint2 o;
            o.x = (unsigned)s;
            o.y = __builtin_bit_cast(unsigned, v);
            ep[pos] = o;
        }
    }
}

// ---------------- gather v2: 1 wave per node, readlane broadcast, unroll-4 ----------------
// out[n] = alpha * sum val*h[col]  (+ beta*init[n]);  h/init/out bf16, fp32 accum
template <int C>
__global__ __launch_bounds__(256) void k_gather2(const unsigned short* __restrict__ h,
                                                 const int* __restrict__ rp,
                                                 const uint2* __restrict__ ep,
                                                 float alpha, const unsigned short* __restrict__ init,
                                                 float beta, unsigned short* __restrict__ out) {
    const int wave = threadIdx.x >> 6;
    const int lane = threadIdx.x & 63;
    const int n = blockIdx.x * 4 + wave;
    if (n >= N_NODES) return;
    const int beg = rp[n], end = rp[n + 1];

    if (C == 128) {
        const unsigned* h2 = (const unsigned*)h;
        float ax = 0.f, ay = 0.f;
        for (int cs = beg; cs < end; cs += 64) {
            const int m = min(64, end - cs);
            uint2 p = {0u, 0u};
            if (lane < m) p = ep[cs + lane];
            int j = 0;
            for (; j + 4 <= m; j += 4) {
                int c0 = __builtin_amdgcn_readlane((int)p.x, j + 0);
                int c1 = __builtin_amdgcn_readlane((int)p.x, j + 1);
                int c2 = __builtin_amdgcn_readlane((int)p.x, j + 2);
                int c3 = __builtin_amdgcn_readlane((int)p.x, j + 3);
                float w0 = __builtin_bit_cast(float, (unsigned)__builtin_amdgcn_readlane((int)p.y, j + 0));
                float w1 = __builtin_bit_cast(float, (unsigned)__builtin_amdgcn_readlane((int)p.y, j + 1));
                float w2 = __builtin_bit_cast(float, (unsigned)__builtin_amdgcn_readlane((int)p.y, j + 2));
                float w3 = __builtin_bit_cast(float, (unsigned)__builtin_amdgcn_readlane((int)p.y, j + 3));
                unsigned q0 = h2[(size_t)c0 * 64 + lane];
                unsigned q1 = h2[(size_t)c1 * 64 + lane];
                unsigned q2 = h2[(size_t)c2 * 64 + lane];
                unsigned q3 = h2[(size_t)c3 * 64 + lane];
                ax = fmaf(w0, b2f_lo(q0), ax); ay = fmaf(w0, b2f_hi(q0), ay);
                ax = fmaf(w1, b2f_lo(q1), ax); ay = fmaf(w1, b2f_hi(q1), ay);
                ax = fmaf(w2, b2f_lo(q2), ax); ay = fmaf(w2, b2f_hi(q2), ay);
                ax = fmaf(w3, b2f_lo(q3), ax); ay = fmaf(w3, b2f_hi(q3), ay);
            }
            for (; j < m; j++) {
                int c0 = __builtin_amdgcn_readlane((int)p.x, j);
                float w0 = __builtin_bit_cast(float, (unsigned)__builtin_amdgcn_readlane((int)p.y, j));
                unsigned q0 = h2[(size_t)c0 * 64 + lane];
                ax = fmaf(w0, b2f_lo(q0), ax); ay = fmaf(w0, b2f_hi(q0), ay);
            }
        }
        float vx = alpha * ax, vy = alpha * ay;
        if (init) {
            unsigned ip = ((const unsigned*)init)[(size_t)n * 64 + lane];
            vx = fmaf(beta, b2f_lo(ip), vx);
            vy = fmaf(beta, b2f_hi(ip), vy);
        }
        ((unsigned*)out)[(size_t)n * 64 + lane] =
            (unsigned)f2b(vx) | ((unsigned)f2b(vy) << 16);
    } else {   // C == 64
        float a = 0.f;
        for (int cs = beg; cs < end; cs += 64) {
            const int m = min(64, end - cs);
            uint2 p = {0u, 0u};
            if (lane < m) p = ep[cs + lane];
            int j = 0;
            for (; j + 4 <= m; j += 4) {
                int c0 = __builtin_amdgcn_readlane((int)p.x, j + 0);
                int c1 = __builtin_amdgcn_readlane((int)p.x, j + 1);
                int c2 = __builtin_amdgcn_readlane((int)p.x, j + 2);
                int c3 = __builtin_amdgcn_readlane((int)p.x, j + 3);
                float w0 = __builtin_bit_cast(float, (unsigned)__builtin_amdgcn_readlane((int)p.y, j + 0));
                float w1 = __builtin_bit_cast(float, (unsigned)__builtin_amdgcn_readlane((int)p.y, j + 1));
                float w2 = __builtin_bit_cast(float, (unsigned)__builtin_amdgcn_readlane((int)p.y, j + 2));
                float w3 = __builtin_bit_cast(float, (unsigned)__builtin_amdgcn_readlane((int)p.y, j + 3));
                float v0 = b2f(h[(size_t)c0 * 64 + lane]);
                float v1 = b2f(h[(size_t)c1 * 64 + lane]);
                float v2 = b2f(h[(size_t)c2 * 64 + lane]);
                float v3 = b2f(h[(size_t)c3 * 64 + lane]);
                a = fmaf(w0, v0, a); a = fmaf(w1, v1, a);
                a = fmaf(w2, v2, a); a = fmaf(w3, v3, a);
            }
            for (; j < m; j++) {
                int c0 = __builtin_amdgcn_readlane((int)p.x, j);
                float w0 = __builtin_bit_cast(float, (unsigned)__builtin_amdgcn_readlane((int)p.y, j));
                a = fmaf(w0, b2f(h[(size_t)c0 * 64 + lane]), a);
            }
        }
        float v = alpha * a;
        if (init) v = fmaf(beta, b2f(init[(size_t)n * 64 + lane]), v);
        out[(size_t)n * 64 + lane] = f2b(v);
    }
}

// ---------------- MFMA GEMM v2: LDS-staged Wt N-slice, 128-row blocks ----------------
// grid (ceil(N/128), COUT/NSL); block 256 (4 waves); wave w: rows w*32..w*32+31 (2 m-frags)
// LDS: Wt slice [NSL][KT] bf16, row padded +8 shorts -> <=2-way bank aliasing (free)
template <int CIN, int COUT, int NSL, bool RELU, bool BF16OUT>
__global__ __launch_bounds__(256) void k_mm2(const unsigned short* __restrict__ t0,
                                             const unsigned short* __restrict__ t1,
                                             const unsigned short* __restrict__ t2,
                                             const unsigned short* __restrict__ Wt,
                                             const float* __restrict__ bias,
                                             void* __restrict__ outv) {
    constexpr int KT = 3 * CIN;
    constexpr int KP = KT + 8;
    constexpr int NFR = NSL / 16;
    __shared__ unsigned short sw[NSL * KP];

    const int tid = threadIdx.x;
    const int n0 = blockIdx.y * NSL;

    // stage Wt[n0..n0+NSL)[0..KT) -> LDS (16B chunks, coalesced)
    constexpr int CHUNKS = NSL * KT / 8;
    for (int i = tid; i < CHUNKS; i += 256) {
        int row = i / (KT / 8);
        int k8 = i % (KT / 8);
        short8 v = *(const short8*)(Wt + (size_t)(n0 + row) * KT + k8 * 8);
        *(short8*)(sw + row * KP + k8 * 8) = v;
    }
    __syncthreads();

    const int wave = tid >> 6, lane = tid & 63;
    const int l16 = lane & 15, quad = lane >> 4;
    const int mBase = blockIdx.x * 128 + wave * 32;
    const int r0 = mBase + l16, r1 = mBase + 16 + l16;
    const bool in0 = r0 < N_NODES, in1 = r1 < N_NODES;

    f32x4 acc[2][NFR] = {};
    const unsigned short* tb[3] = {t0, t1, t2};
    const short8 zero8 = {0, 0, 0, 0, 0, 0, 0, 0};

    #pragma unroll
    for (int kt = 0; kt < KT / 32; kt++) {
        const int kb = kt * 32;
        const unsigned short* t = tb[kb / CIN];
        const int kin = (kb % CIN) + quad * 8;
        short8 a0 = zero8, a1 = zero8;
        if (in0) a0 = *(const short8*)(t + (size_t)r0 * CIN + kin);
        if (in1) a1 = *(const short8*)(t + (size_t)r1 * CIN + kin);
        #pragma unroll
        for (int nf = 0; nf < NFR; nf++) {
            const short8 b = *(const short8*)(sw + (nf * 16 + l16) * KP + kb + quad * 8);
            acc[0][nf] = __builtin_amdgcn_mfma_f32_16x16x32_bf16(a0, b, acc[0][nf], 0, 0, 0);
            acc[1][nf] = __builtin_amdgcn_mfma_f32_16x16x32_bf16(a1, b, acc[1][nf], 0, 0, 0);
        }
    }

    // C/D layout: col = lane&15, row = quad*4 + reg
    #pragma unroll
    for (int mi = 0; mi < 2; mi++) {
        #pragma unroll
        for (int nf = 0; nf < NFR; nf++) {
            #pragma unroll
            for (int r = 0; r < 4; r++) {
                const int node = mBase + mi * 16 + quad * 4 + r;
                if (node < N_NODES) {
                    const int co = n0 + nf * 16 + l16;
                    float o = acc[mi][nf][r] + bias[co];
                    if (RELU) o = fmaxf(o, 0.f);
                    if (BF16OUT)
                        ((unsigned short*)outv)[(size_t)node * COUT + co] = f2b(o);
                    else
                        ((float*)outv)[(size_t)node * COUT + co] = o;
                }
            }
        }
    }
}

// ---------------- launch ----------------
static inline int ceil_div(int a, int b) { return (a + b - 1) / b; }

extern "C" void kernel_launch(void* const* d_in, const int* in_sizes, int n_in,
                              void* d_out, int out_size, void* d_ws, size_t ws_size,
                              hipStream_t stream) {
    const float* x   = (const float*)d_in[0];
    const int*   ei  = (const int*)d_in[1];
    const int*   src = ei;
    const int*   dst = ei + N_EDGES;
    const float* W1 = (const float*)d_in[3];
    const float* b1 = (const float*)d_in[4];
    const float* W2 = (const float*)d_in[5];
    const float* b2 = (const float*)d_in[6];
    const float* W3 = (const float*)d_in[7];
    const float* b3 = (const float*)d_in[8];
    float* out = (float*)d_out;

    // workspace layout (8B-aligned first)
    char* p = (char*)d_ws;
    uint2* ep     = (uint2*)p;           p += (size_t)N_EDGES * 8;
    float* dinv   = (float*)p;           p += (size_t)N_NODES * 4;
    int*   degin  = (int*)p;             p += (size_t)N_NODES * 4;
    int*   rp     = (int*)p;             p += (size_t)(N_NODES + 4) * 4;
    int*   cursor = (int*)p;             p += (size_t)N_NODES * 4;
    unsigned short* xb   = (unsigned short*)p; p += (size_t)N_NODES * 128 * 2;
    unsigned short* tx1b = (unsigned short*)p; p += (size_t)N_NODES * 128 * 2;
    unsigned short* tx2b = (unsigned short*)p; p += (size_t)N_NODES * 128 * 2;
    unsigned short* h1b  = (unsigned short*)p; p += (size_t)N_NODES * 64 * 2;
    unsigned short* h2b  = (unsigned short*)p; p += (size_t)N_NODES * 128 * 2;
    unsigned short* Wt1  = (unsigned short*)p; p += (size_t)64 * 384 * 2;
    unsigned short* Wt2  = (unsigned short*)p; p += (size_t)128 * 192 * 2;
    unsigned short* Wt3  = (unsigned short*)p; p += (size_t)256 * 384 * 2;

    const int TB = 256;
    const int gE = ceil_div(N_EDGES, TB);
    const int gN = ceil_div(N_NODES, TB);
    const int gG = ceil_div(N_NODES, 4);     // gather: 4 nodes per 256-thr block
    const int gM = ceil_div(N_NODES, 128);   // mm2: 128 rows per block

    // conversions
    k_f2b<<<ceil_div(N_NODES * 128 / 4, TB), TB, 0, stream>>>(x, xb, N_NODES * 128 / 4);
    k_wt<<<ceil_div(384 * 64, TB), TB, 0, stream>>>(W1, Wt1, 384, 64);
    k_wt<<<ceil_div(192 * 128, TB), TB, 0, stream>>>(W2, Wt2, 192, 128);
    k_wt<<<ceil_div(384 * 256, TB), TB, 0, stream>>>(W3, Wt3, 384, 256);

    // edge weights + dst-CSR
    hipMemsetAsync(dinv, 0, N_NODES * sizeof(float), stream);
    hipMemsetAsync(degin, 0, N_NODES * sizeof(int), stream);
    k_degboth<<<gE, TB, 0, stream>>>(src, dst, dinv, degin);
    k_dinv<<<gN, TB, 0, stream>>>(dinv);
    k_scan<<<1, 1024, 0, stream>>>(degin, rp, cursor);
    k_scatter<<<gE, TB, 0, stream>>>(src, dst, dinv, cursor, ep);

    // ---- layer 1: 128 -> 64, relu ----
    k_gather2<128><<<gG, TB, 0, stream>>>(xb, rp, ep, 1.f, nullptr, 0.f, tx1b);
    k_gather2<128><<<gG, TB, 0, stream>>>(tx1b, rp, ep, 2.f, xb, -1.f, tx2b);
    k_mm2<128, 64, 64, true, true><<<dim3(gM, 1), TB, 0, stream>>>(xb, tx1b, tx2b, Wt1, b1, h1b);

    // ---- layer 2: 64 -> 128, relu ----
    k_gather2<64><<<gG, TB, 0, stream>>>(h1b, rp, ep, 1.f, nullptr, 0.f, tx1b);
    k_gather2<64><<<gG, TB, 0, stream>>>(tx1b, rp, ep, 2.f, h1b, -1.f, tx2b);
    k_mm2<64, 128, 128, true, true><<<dim3(gM, 1), TB, 0, stream>>>(h1b, tx1b, tx2b, Wt2, b2, h2b);

    // ---- layer 3: 128 -> 256, no relu ----
    k_gather2<128><<<gG, TB, 0, stream>>>(h2b, rp, ep, 1.f, nullptr, 0.f, tx1b);
    k_gather2<128><<<gG, TB, 0, stream>>>(tx1b, rp, ep, 2.f, h2b, -1.f, tx2b);
    k_mm2<128, 256, 64, false, false><<<dim3(gM, 4), TB, 0, stream>>>(h2b, tx1b, tx2b, Wt3, b3, out);
}